// Round 8
// baseline (32.321 us; speedup 1.0000x reference)
//
#include <hip/hip_runtime.h>

// 5x5 median, replicate borders, C=3, H=W=2048, fp32.
// Single fused kernel, branch-free, packed-bf16 (error <= 2^-9 << 1.88e-2).
// Pixel pairs (x, x+4) in u32 lanes; network on v_pk_min_u16/v_pk_max_u16.
// Per thread = 8 pixels (x = 8g..8g+7) as 4 packed pairs:
//   P[j] = pack(col_{8g-2+j} -> lo, col_{8g+2+j} -> hi), j = 0..7
//   8x sort5 + merge55 on (P1,P2),(P3,P4),(P5,P6) + 2 shared mid6 + 4 rank5.
// R8 change: ALL 20 row-loads hoisted into register arrays before any packing,
// so the loads pipeline (1 latency exposure instead of 5 serialized trips).

typedef unsigned int u32;

__device__ __forceinline__ u32 pmn(u32 a, u32 b) {
    u32 r;
    asm("v_pk_min_u16 %0, %1, %2" : "=v"(r) : "v"(a), "v"(b));
    return r;
}
__device__ __forceinline__ u32 pmx(u32 a, u32 b) {
    u32 r;
    asm("v_pk_max_u16 %0, %1, %2" : "=v"(r) : "v"(a), "v"(b));
    return r;
}

#define PCE(i, j)                     \
    {                                 \
        u32 a_ = v[i], b_ = v[j];     \
        v[i] = pmn(a_, b_);           \
        v[j] = pmx(a_, b_);           \
    }

// Knuth's optimal 9-CE sorting network for 5 (packed).
__device__ __forceinline__ void sort5p(u32 (&v)[5]) {
    PCE(0, 1) PCE(3, 4) PCE(2, 4) PCE(2, 3) PCE(0, 3) PCE(0, 2) PCE(1, 4) PCE(1, 3) PCE(1, 2)
}

// Batcher odd-even merge of two sorted 5-arrays -> sorted 10 (packed). 13 CEs.
__device__ __forceinline__ void merge55p(const u32 (&A)[5], const u32 (&B)[5], u32 (&C)[10]) {
    u32 re0 = pmn(A[0], B[0]), re1 = pmx(A[0], B[0]);
    u32 ro0 = pmn(A[4], B[4]), ro1 = pmx(A[4], B[4]);
    u32 R1 = pmn(re1, ro0), R2 = pmx(re1, ro0);
    u32 s0 = pmn(A[2], B[2]), s1 = pmx(A[2], B[2]);
    u32 P1 = pmn(R1, s0), P2 = pmx(R1, s0);
    u32 P3 = pmn(R2, s1), P4 = pmx(R2, s1);
    u32 qe0 = pmn(A[1], B[1]), qe1 = pmx(A[1], B[1]);
    u32 qo0 = pmn(A[3], B[3]), qo1 = pmx(A[3], B[3]);
    u32 Q1 = pmn(qe1, qo0), Q2 = pmx(qe1, qo0);
    C[0] = re0;
    C[1] = pmn(P1, qe0); C[2] = pmx(P1, qe0);
    C[3] = pmn(P2, Q1);  C[4] = pmx(P2, Q1);
    C[5] = pmn(P3, Q2);  C[6] = pmx(P3, Q2);
    C[7] = pmn(P4, qo1); C[8] = pmx(P4, qo1);
    C[9] = ro1;
}

// Middle six (ranks 7..12, sorted) of merge(S10,T10): pruned Batcher merge.
__device__ __forceinline__ void mid6p(const u32 (&S)[10], const u32 (&T)[10], u32 (&V)[6]) {
    u32 e1 = pmx(S[0], T[0]);
    u32 o0 = pmn(S[8], T[8]);
    u32 R1 = pmn(e1, o0), R2 = pmx(e1, o0);
    u32 s0 = pmn(S[4], T[4]), s1 = pmx(S[4], T[4]);
    u32 qe1 = pmx(S[2], T[2]), qo0 = pmn(S[6], T[6]);
    u32 Q1 = pmn(qe1, qo0), Q2 = pmx(qe1, qo0);
    u32 E4 = pmx(pmx(R1, s0), Q1);
    u32 P3 = pmn(R2, s1);
    u32 E5 = pmn(P3, Q2), E6 = pmx(P3, Q2);
    u32 f1 = pmx(S[1], T[1]);
    u32 g0 = pmn(S[9], T[9]);
    u32 R1o = pmn(f1, g0), R2o = pmx(f1, g0);
    u32 t0 = pmn(S[5], T[5]), t1 = pmx(S[5], T[5]);
    u32 qf1 = pmx(S[3], T[3]), qg0 = pmn(S[7], T[7]);
    u32 Q1o = pmn(qf1, qg0), Q2o = pmx(qf1, qg0);
    u32 P2o = pmx(R1o, t0);
    u32 O3 = pmn(P2o, Q1o), O4 = pmx(P2o, Q1o);
    u32 O5 = pmn(pmn(R2o, t1), Q2o);
    V[0] = pmn(E4, O3); V[1] = pmx(E4, O3);
    V[2] = pmn(E5, O4); V[3] = pmx(E5, O4);
    V[4] = pmn(E6, O5); V[5] = pmx(E6, O5);
}

// rank-5 of V(6 sorted) u G(5 sorted): max over splits of min(V[i],G[j]).
__device__ __forceinline__ u32 rank5p(const u32 (&V)[6], const u32 (&G)[5]) {
    u32 m1 = pmn(V[1], G[4]);
    u32 m2 = pmn(V[2], G[3]);
    u32 m3 = pmn(V[3], G[2]);
    u32 m4 = pmn(V[4], G[1]);
    u32 m5 = pmn(V[5], G[0]);
    return pmx(pmx(pmx(V[0], m1), m2), pmx(pmx(m3, m4), m5));
}

__global__ __launch_bounds__(256, 2) void median5x5_all(const u32* __restrict__ in,
                                                        u32* __restrict__ out) {
    const int W = 2048, H = 2048;
    const int g = blockIdx.x * 64 + threadIdx.x;  // 0..255; pixels 8g..8g+7
    const int y = blockIdx.y * 4 + threadIdx.y;
    const size_t plane = (size_t)blockIdx.z * (size_t)(H * W);
    const u32* __restrict__ src = in + plane;

    // Clamped outer-load columns (8B-aligned in all cases).
    const int base = 8 * g;
    const int colA = (base - 2) < 0 ? 0 : (base - 2);        // raw[0,1]
    const int colD = (base + 8) > 2046 ? 2046 : (base + 8);  // raw[10,11]
    const bool g0 = (g == 0);
    const bool g255 = (g == 255);

    // ---- phase 1: issue ALL 20 loads (5 rows x 4 vectors), no packing ----
    uint2 A[5], D[5];
    uint4 B[5], C[5];
#pragma unroll
    for (int r = 0; r < 5; ++r) {
        int yy = y - 2 + r;
        yy = yy < 0 ? 0 : (yy > H - 1 ? H - 1 : yy);
        const u32* rowp = src + (size_t)yy * W;
        A[r] = *(const uint2*)(rowp + colA);
        B[r] = *(const uint4*)(rowp + base);
        C[r] = *(const uint4*)(rowp + base + 4);
        D[r] = *(const uint2*)(rowp + colD);
    }

    // ---- phase 2: pack to bf16x2 columns (in-order vmcnt overlaps w/ loads) ----
    // raw[j] = col base-2+j; fixups: raw[1] = g0 ? A.x : A.y,
    // raw[10] = g255 ? D.y : D.x; raw[0]=A.x, raw[11]=D.y always correct.
    // v_perm selector 0x07060302 = high 16 bits of each f32 = bf16 truncation.
    u32 P[8][5];
#pragma unroll
    for (int r = 0; r < 5; ++r) {
        u32 raw[12];
        raw[0] = A[r].x;
        raw[1] = g0 ? A[r].x : A[r].y;
        raw[2] = B[r].x;  raw[3] = B[r].y;  raw[4] = B[r].z;  raw[5] = B[r].w;
        raw[6] = C[r].x;  raw[7] = C[r].y;  raw[8] = C[r].z;  raw[9] = C[r].w;
        raw[10] = g255 ? D[r].y : D[r].x;
        raw[11] = D[r].y;
#pragma unroll
        for (int j = 0; j < 8; ++j)
            P[j][r] = __builtin_amdgcn_perm(raw[j + 4], raw[j], 0x07060302u);
    }

    // ---- phase 3: packed selection network ----
#pragma unroll
    for (int j = 0; j < 8; ++j) sort5p(P[j]);

    u32 M12[10], M34[10], M56[10];
    merge55p(P[1], P[2], M12);
    merge55p(P[3], P[4], M34);
    merge55p(P[5], P[6], M56);

    u32 VA[6], VB[6];
    mid6p(M12, M34, VA);  // windows P[0..4] and P[1..5]
    mid6p(M34, M56, VB);  // windows P[2..6] and P[3..7]

    u32 o0 = rank5p(VA, P[0]);
    u32 o1 = rank5p(VA, P[5]);
    u32 o2 = rank5p(VB, P[2]);
    u32 o3 = rank5p(VB, P[7]);

    // lo half -> pixel 8g+i, hi half -> pixel 8g+4+i (bf16 -> f32 = shift/mask)
    u32* op = out + plane + (size_t)y * W + base;
    uint4 e, o;
    e.x = o0 << 16; e.y = o1 << 16; e.z = o2 << 16; e.w = o3 << 16;
    o.x = o0 & 0xffff0000u; o.y = o1 & 0xffff0000u;
    o.z = o2 & 0xffff0000u; o.w = o3 & 0xffff0000u;
    *(uint4*)(op) = e;
    *(uint4*)(op + 4) = o;
}

extern "C" void kernel_launch(void* const* d_in, const int* in_sizes, int n_in,
                              void* d_out, int out_size, void* d_ws, size_t ws_size,
                              hipStream_t stream) {
    const u32* in = (const u32*)d_in[0];
    u32* out = (u32*)d_out;
    dim3 block(64, 4, 1);
    dim3 grid(4, 512, 3);
    hipLaunchKernelGGL(median5x5_all, grid, block, 0, stream, in, out);
}